// Round 4
// baseline (182.388 us; speedup 1.0000x reference)
//
#include <hip/hip_runtime.h>

// ---------------------------------------------------------------------------
// Causal MHSA. B=2, T=2048, D=1024, H=16, hd=64. fp32 in -> bf16 internal ->
// fp32 out. R15: (1) attn mapping reverted to R11 exact (dim3(32,32),
// qt=31-y; proven 48.2us; placement arithmetic abandoned after R13/R14);
// (2) attn softmax P-pack + output pack via v_cvt_pk_bf16_f32 (T12) — cuts
// ~40 VALU/tile-unit; (3) GEMMs BK=64 with split k-half LDS buffers
// ([128][32] x2 per matrix: keeps conflict-optimal 64B rows + linear
// global_load_lds dests) — halves barrier-drain count per block.
// ---------------------------------------------------------------------------

#define T_SEQ 2048
#define D_MODEL 1024
#define NEG_BIG (-1.0e30f)
#define Q_SCALE 0.18033688f   // 0.125 * log2(e): attention uses exp2 directly

typedef float f32x4 __attribute__((ext_vector_type(4)));
typedef short s16x8 __attribute__((ext_vector_type(8)));
typedef __bf16 bf16x8 __attribute__((ext_vector_type(8)));

__device__ __forceinline__ f32x4 mfma16(s16x8 a, s16x8 b, f32x4 c) {
    // C[m][n]=sum_k A[m][k]B[n][k]; lane: a=A[m=l16][k=quad*8+j],
    // b=B[n=l16][k=quad*8+j]; C: col(l16)=n, row(quad*4+r)=m
    return __builtin_amdgcn_mfma_f32_16x16x32_bf16(
        __builtin_bit_cast(bf16x8, a), __builtin_bit_cast(bf16x8, b), c, 0, 0, 0);
}

__device__ __forceinline__ short f2bf(float f) {          // RNE
    unsigned int u = __float_as_uint(f);
    u += 0x7fffu + ((u >> 16) & 1u);
    return (short)(u >> 16);
}
__device__ __forceinline__ float bf2f(short s) {
    return __uint_as_float(((unsigned int)(unsigned short)s) << 16);
}
__device__ __forceinline__ unsigned cvt_pk_bf16(float lo, float hi) {
    unsigned r;
    asm("v_cvt_pk_bf16_f32 %0, %1, %2" : "=v"(r) : "v"(lo), "v"(hi));
    return r;
}

__device__ __forceinline__ void async_lds16(const short* g, short* l) {
    __builtin_amdgcn_global_load_lds(
        (const __attribute__((address_space(1))) unsigned int*)g,
        (__attribute__((address_space(3))) unsigned int*)l, 16, 0, 0);
}

// ---------------------------------------------------------------------------
// Fused canon: five fp32 inputs -> bf16, float4-vectorized, one launch.
// ---------------------------------------------------------------------------
#define N_X   4194304
#define N_WI  3145728
#define N_BI  3072
#define N_WO  1048576
#define N_BO  1024
#define V_X   (N_X  / 4)
#define V_WI  (N_WI / 4)
#define V_BI  (N_BI / 4)
#define V_WO  (N_WO / 4)
#define V_BO  (N_BO / 4)
#define V_TOT (V_X + V_WI + V_BI + V_WO + V_BO)

__global__ __launch_bounds__(256) void canon_all_kernel(
    const float* __restrict__ x, const float* __restrict__ wi,
    const float* __restrict__ bi, const float* __restrict__ wo,
    const float* __restrict__ bo,
    short* __restrict__ xb, short* __restrict__ wib, short* __restrict__ bib,
    short* __restrict__ wob, short* __restrict__ bob)
{
    int i = blockIdx.x * 256 + threadIdx.x;
    if (i >= V_TOT) return;
    const float* src; short* dst; int off;
    if      (i < V_X)                    { src = x;  dst = xb;  off = i; }
    else if (i < V_X+V_WI)               { src = wi; dst = wib; off = i - V_X; }
    else if (i < V_X+V_WI+V_BI)          { src = bi; dst = bib; off = i - V_X - V_WI; }
    else if (i < V_X+V_WI+V_BI+V_WO)     { src = wo; dst = wob; off = i - V_X - V_WI - V_BI; }
    else                                 { src = bo; dst = bob; off = i - V_X - V_WI - V_BI - V_WO; }
    float4 v = ((const float4*)src)[off];
    short4 o = { f2bf(v.x), f2bf(v.y), f2bf(v.z), f2bf(v.w) };
    ((short4*)dst)[off] = o;
}

// ---------------------------------------------------------------------------
// GEMM1 (BK=64, split k-half buffers): qkv = x @ w_in^T + b_in.
// q(xQ_SCALE)/k -> [B,H,T,64]; v -> Vt [B,H,64,T] (transpose fused).
// ---------------------------------------------------------------------------
__global__ __launch_bounds__(256) void gemm_qkv_kernel(
    const short* __restrict__ A, const short* __restrict__ B,
    const short* __restrict__ bias,
    short* __restrict__ qo, short* __restrict__ ko, short* __restrict__ vto)
{
    const int K = 1024;
    alignas(16) __shared__ short As0[128][32];   // k-half 0
    alignas(16) __shared__ short As1[128][32];   // k-half 1
    alignas(16) __shared__ short Bs0[128][32];
    alignas(16) __shared__ short Bs1[128][32];
    const int m0 = blockIdx.x * 128;
    const int n0 = blockIdx.y * 128;
    const int tid = threadIdx.x;
    const int lane = tid & 63;
    const int w = tid >> 6;
    const int wm = (w >> 1) * 64, wn = (w & 1) * 64;
    const int quad = lane >> 4, l16 = lane & 15;

    f32x4 acc[4][4];
    const f32x4 zero = {0.f, 0.f, 0.f, 0.f};
#pragma unroll
    for (int i = 0; i < 4; ++i)
#pragma unroll
        for (int j = 0; j < 4; ++j) acc[i][j] = zero;

    // staging: wave w owns rows w*32..w*32+31 of each matrix; per gload_lds
    // instr: 64 lanes x 16B = 16 rows x 64B (rows base+(lane>>2), chunk lane&3)
    const int lrow = lane >> 2;              // 0..15
    const int lcol = (lane & 3) * 8;         // 0..24 shorts
    const short* gA00 = &A[(m0 + w*32      + lrow) * K + lcol];       // half0 rows 0-15
    const short* gA01 = &A[(m0 + w*32 + 16 + lrow) * K + lcol];       // half0 rows 16-31
    const short* gA10 = gA00 + 32;                                     // half1
    const short* gA11 = gA01 + 32;
    const short* gB00 = &B[(n0 + w*32      + lrow) * K + lcol];
    const short* gB01 = &B[(n0 + w*32 + 16 + lrow) * K + lcol];
    const short* gB10 = gB00 + 32;
    const short* gB11 = gB01 + 32;
    short* lA00 = &As0[w*32][0];
    short* lA01 = &As0[w*32 + 16][0];
    short* lA10 = &As1[w*32][0];
    short* lA11 = &As1[w*32 + 16][0];
    short* lB00 = &Bs0[w*32][0];
    short* lB01 = &Bs0[w*32 + 16][0];
    short* lB10 = &Bs1[w*32][0];
    short* lB11 = &Bs1[w*32 + 16][0];

    for (int k0 = 0; k0 < K; k0 += 64) {
        __syncthreads();
        async_lds16(gA00 + k0, lA00);
        async_lds16(gA01 + k0, lA01);
        async_lds16(gA10 + k0, lA10);
        async_lds16(gA11 + k0, lA11);
        async_lds16(gB00 + k0, lB00);
        async_lds16(gB01 + k0, lB01);
        async_lds16(gB10 + k0, lB10);
        async_lds16(gB11 + k0, lB11);
        __syncthreads();

        s16x8 af[4], bfr[4];
        // k-half 0
#pragma unroll
        for (int i = 0; i < 4; ++i) af[i]  = *(const s16x8*)&As0[wm + i*16 + l16][quad*8];
#pragma unroll
        for (int j = 0; j < 4; ++j) bfr[j] = *(const s16x8*)&Bs0[wn + j*16 + l16][quad*8];
#pragma unroll
        for (int i = 0; i < 4; ++i)
#pragma unroll
            for (int j = 0; j < 4; ++j)
                acc[i][j] = mfma16(af[i], bfr[j], acc[i][j]);
        // k-half 1
#pragma unroll
        for (int i = 0; i < 4; ++i) af[i]  = *(const s16x8*)&As1[wm + i*16 + l16][quad*8];
#pragma unroll
        for (int j = 0; j < 4; ++j) bfr[j] = *(const s16x8*)&Bs1[wn + j*16 + l16][quad*8];
#pragma unroll
        for (int i = 0; i < 4; ++i)
#pragma unroll
            for (int j = 0; j < 4; ++j)
                acc[i][j] = mfma16(af[i], bfr[j], acc[i][j]);
    }

#pragma unroll
    for (int j = 0; j < 4; ++j) {
        int n = n0 + wn + j*16 + l16;
        float bi = bf2f(bias[n]);
        int which = n >> 10;            // wave-uniform (16 consecutive n)
        int h = (n >> 6) & 15, d = n & 63;
        if (which < 2) {                // Q / K: [B,H,T,64]
            short* dst = (which == 0) ? qo : ko;
            float scl = (which == 0) ? Q_SCALE : 1.0f;
#pragma unroll
            for (int i = 0; i < 4; ++i) {
#pragma unroll
                for (int r = 0; r < 4; ++r) {
                    int m = m0 + wm + i*16 + quad*4 + r;
                    int b = m >> 11, t = m & 2047;
                    float v = (acc[i][j][r] + bi) * scl;
                    dst[(((b*16 + h) * 2048) + t) * 64 + d] = f2bf(v);
                }
            }
        } else {                        // V: write transposed [B,H,64,T]
#pragma unroll
            for (int i = 0; i < 4; ++i) {
                int m = m0 + wm + i*16 + quad*4;   // t0, %4 == 0
                int b = m >> 11, t0 = m & 2047;
                short4 o4 = { f2bf(acc[i][j][0] + bi), f2bf(acc[i][j][1] + bi),
                              f2bf(acc[i][j][2] + bi), f2bf(acc[i][j][3] + bi) };
                *(short4*)&vto[(((size_t)(b*16 + h) * 64) + d) * 2048 + t0] = o4;
            }
        }
    }
}

// ---------------------------------------------------------------------------
// Flash attention — R11 exact structure & mapping (proven 48.2us):
// dim3(32,32), bh=blockIdx.x (XCD=bh%8 L2 locality), qt=31-blockIdx.y
// (heavy-first). Only change vs R11: cvt_pk_bf16 packing (T12) for P and O.
// ---------------------------------------------------------------------------
__global__ __launch_bounds__(256) void attn_kernel(
    const short* __restrict__ Q, const short* __restrict__ K,
    const short* __restrict__ Vt, short* __restrict__ ctx)
{
    alignas(16) __shared__ short Ks[64][72];      // [s][d]
    alignas(16) __shared__ short Vs[64][72];      // [d][s]
    alignas(16) __shared__ short Pl[4][16][72];   // per-wave [q][s]

    const int bh = blockIdx.x;
    const int qt = 31 - (int)blockIdx.y;          // heavy tiles first
    const int qbase = qt * 64;
    const int tid = threadIdx.x;
    const int w = tid >> 6, lane = tid & 63;
    const int quad = lane >> 4, l16 = lane & 15;
    const int b = bh >> 4, h = bh & 15;

    const short* Qb  = Q  + bh * T_SEQ * 64;
    const short* Kb  = K  + bh * T_SEQ * 64;
    const short* Vbt = Vt + (size_t)bh * 64 * T_SEQ;

    const short* qrow = Qb + (qbase + w*16 + l16) * 64;
    const s16x8 qa0 = *(const s16x8*)(qrow + quad*8);
    const s16x8 qa1 = *(const s16x8*)(qrow + 32 + quad*8);

    const f32x4 zero = {0.f, 0.f, 0.f, 0.f};
    f32x4 o[4];
#pragma unroll
    for (int dt = 0; dt < 4; ++dt) o[dt] = zero;
    float lsum = 0.f;

    const int sr  = tid >> 3;                     // 0..31
    const int scl = (tid & 7) * 8;                // 0..56
    const int qg  = qbase + w*16 + l16;

    // preload tile s0=0
    float4 kf0 = *(const float4*)&Kb[sr * 64 + scl];
    float4 kf1 = *(const float4*)&Kb[(sr + 32) * 64 + scl];
    float4 vf0 = *(const float4*)&Vbt[(size_t)sr * T_SEQ + scl];
    float4 vf1 = *(const float4*)&Vbt[(size_t)(sr + 32) * T_SEQ + scl];

    for (int s0 = 0; s0 <= qbase; s0 += 64) {
        __syncthreads();
        *(float4*)&Ks[sr][scl]    = kf0;
        *(float4*)&Ks[sr+32][scl] = kf1;
        *(float4*)&Vs[sr][scl]    = vf0;
        *(float4*)&Vs[sr+32][scl] = vf1;
        __syncthreads();

        if (s0 + 64 <= qbase) {                   // prefetch next tile
            kf0 = *(const float4*)&Kb[(s0 + 64 + sr) * 64 + scl];
            kf1 = *(const float4*)&Kb[(s0 + 64 + sr + 32) * 64 + scl];
            vf0 = *(const float4*)&Vbt[(size_t)sr * T_SEQ + s0 + 64 + scl];
            vf1 = *(const float4*)&Vbt[(size_t)(sr + 32) * T_SEQ + s0 + 64 + scl];
        }

        // S^T = K Q^T
#pragma unroll
        for (int sub = 0; sub < 4; ++sub) {
            s16x8 ka0 = *(const s16x8*)&Ks[sub*16 + l16][quad*8];
            s16x8 ka1 = *(const s16x8*)&Ks[sub*16 + l16][32 + quad*8];
            f32x4 S = mfma16(ka1, qa1, mfma16(ka0, qa0, zero));
            if (s0 == qbase) {                    // diagonal: causal mask
                int sb = s0 + sub*16 + quad*4;
#pragma unroll
                for (int r = 0; r < 4; ++r)
                    if (sb + r > qg) S[r] = NEG_BIG;
            }
            float p0 = exp2f(S[0]), p1 = exp2f(S[1]);
            float p2 = exp2f(S[2]), p3 = exp2f(S[3]);
            lsum += (p0 + p1) + (p2 + p3);
            uint2 pk;
            pk.x = cvt_pk_bf16(p0, p1);
            pk.y = cvt_pk_bf16(p2, p3);
            *(uint2*)&Pl[w][l16][sub*16 + quad*4] = pk;
        }
        // wave-private Pl: in-order within wave, no barrier

        // O^T += V^T P^T
        s16x8 pb0 = *(const s16x8*)&Pl[w][l16][quad*8];
        s16x8 pb1 = *(const s16x8*)&Pl[w][l16][32 + quad*8];
#pragma unroll
        for (int dt = 0; dt < 4; ++dt) {
            s16x8 va0 = *(const s16x8*)&Vs[dt*16 + l16][quad*8];
            s16x8 va1 = *(const s16x8*)&Vs[dt*16 + l16][32 + quad*8];
            o[dt] = mfma16(va1, pb1, mfma16(va0, pb0, o[dt]));
        }
    }

    lsum += __shfl_xor(lsum, 16, 64);
    lsum += __shfl_xor(lsum, 32, 64);
    float inv = 1.0f / lsum;
    int base = (b * T_SEQ + qg) * D_MODEL + h * 64;
#pragma unroll
    for (int dt = 0; dt < 4; ++dt) {
        uint2 pk;
        pk.x = cvt_pk_bf16(o[dt][0] * inv, o[dt][1] * inv);
        pk.y = cvt_pk_bf16(o[dt][2] * inv, o[dt][3] * inv);
        *(uint2*)&ctx[base + dt*16 + quad*4] = pk;
    }
}

// ---------------------------------------------------------------------------
// GEMM2 (BK=64, split k-half buffers): out = ctx @ w_out^T + b_out, fp32.
// 128x64 tiles, 512 blocks.
// ---------------------------------------------------------------------------
__global__ __launch_bounds__(256) void gemm_out_kernel(
    const short* __restrict__ A, const short* __restrict__ B,
    const short* __restrict__ bias, float* __restrict__ out)
{
    const int K = 1024;
    alignas(16) __shared__ short As0[128][32];
    alignas(16) __shared__ short As1[128][32];
    alignas(16) __shared__ short Bs0[64][32];
    alignas(16) __shared__ short Bs1[64][32];
    const int m0 = blockIdx.x * 128;
    const int n0 = blockIdx.y * 64;
    const int tid = threadIdx.x;
    const int lane = tid & 63;
    const int w = tid >> 6;
    const int wm = (w >> 1) * 64, wn = (w & 1) * 32;
    const int quad = lane >> 4, l16 = lane & 15;

    f32x4 acc[4][2];
    const f32x4 zero = {0.f, 0.f, 0.f, 0.f};
#pragma unroll
    for (int i = 0; i < 4; ++i)
#pragma unroll
        for (int j = 0; j < 2; ++j) acc[i][j] = zero;

    const int lrow = lane >> 2;
    const int lcol = (lane & 3) * 8;
    const short* gA00 = &A[(m0 + w*32      + lrow) * K + lcol];
    const short* gA01 = &A[(m0 + w*32 + 16 + lrow) * K + lcol];
    const short* gA10 = gA00 + 32;
    const short* gA11 = gA01 + 32;
    const short* gB00 = &B[(n0 + w*16 + lrow) * K + lcol];
    const short* gB10 = gB00 + 32;
    short* lA00 = &As0[w*32][0];
    short* lA01 = &As0[w*32 + 16][0];
    short* lA10 = &As1[w*32][0];
    short* lA11 = &As1[w*32 + 16][0];
    short* lB00 = &Bs0[w*16][0];
    short* lB10 = &Bs1[w*16][0];

    for (int k0 = 0; k0 < K; k0 += 64) {
        __syncthreads();
        async_lds16(gA00 + k0, lA00);
        async_lds16(gA01 + k0, lA01);
        async_lds16(gA10 + k0, lA10);
        async_lds16(gA11 + k0, lA11);
        async_lds16(gB00 + k0, lB00);
        async_lds16(gB10 + k0, lB10);
        __syncthreads();

        s16x8 af[4], bfr[2];
        // k-half 0
#pragma unroll
        for (int i = 0; i < 4; ++i) af[i]  = *(const s16x8*)&As0[wm + i*16 + l16][quad*8];
#pragma unroll
        for (int j = 0; j < 2; ++j) bfr[j] = *(const s16x8*)&Bs0[wn + j*16 + l16][quad*8];
#pragma unroll
        for (int i = 0; i < 4; ++i)
#pragma unroll
            for (int j = 0; j < 2; ++j)
                acc[i][j] = mfma16(af[i], bfr[j], acc[i][j]);
        // k-half 1
#pragma unroll
        for (int i = 0; i < 4; ++i) af[i]  = *(const s16x8*)&As1[wm + i*16 + l16][quad*8];
#pragma unroll
        for (int j = 0; j < 2; ++j) bfr[j] = *(const s16x8*)&Bs1[wn + j*16 + l16][quad*8];
#pragma unroll
        for (int i = 0; i < 4; ++i)
#pragma unroll
            for (int j = 0; j < 2; ++j)
                acc[i][j] = mfma16(af[i], bfr[j], acc[i][j]);
    }

#pragma unroll
    for (int j = 0; j < 2; ++j) {
        int n = n0 + wn + j*16 + l16;
        float bi = bf2f(bias[n]);
#pragma unroll
        for (int i = 0; i < 4; ++i) {
#pragma unroll
            for (int r = 0; r < 4; ++r) {
                int m = m0 + wm + i*16 + quad*4 + r;
                out[m * 1024 + n] = acc[i][j][r] + bi;
            }
        }
    }
}

// ---------------------------------------------------------------------------
extern "C" void kernel_launch(void* const* d_in, const int* in_sizes, int n_in,
                              void* d_out, int out_size, void* d_ws, size_t ws_size,
                              hipStream_t stream) {
    float* out = (float*)d_out;
    char* ws = (char*)d_ws;

    const size_t MB = 1u << 20;
    short* xb     = (short*)(ws);            // 8 MB
    short* w_inb  = (short*)(ws + 8*MB);     // 6 MB
    short* b_inb  = (short*)(ws + 14*MB);
    short* w_outb = (short*)(ws + 15*MB);    // 2 MB
    short* b_outb = (short*)(ws + 17*MB);
    short* qb     = (short*)(ws + 18*MB);    // 8 MB [B,H,T,64]
    short* kb     = (short*)(ws + 26*MB);    // 8 MB [B,H,T,64]
    short* vtb    = (short*)(ws + 34*MB);    // 8 MB [B,H,64,T] (direct from gemm)
    short* ctxb   = (short*)(ws + 42*MB);    // 8 MB [B,T,D]

    canon_all_kernel<<<(V_TOT + 255) / 256, 256, 0, stream>>>(
        (const float*)d_in[0], (const float*)d_in[1], (const float*)d_in[2],
        (const float*)d_in[3], (const float*)d_in[4],
        xb, w_inb, b_inb, w_outb, b_outb);

    gemm_qkv_kernel<<<dim3(32, 24), 256, 0, stream>>>(xb, w_inb, b_inb, qb, kb, vtb);
    attn_kernel<<<dim3(32, 32), 256, 0, stream>>>(qb, kb, vtb, ctxb);
    gemm_out_kernel<<<dim3(32, 16), 256, 0, stream>>>(ctxb, w_outb, b_outb, out);
}

// Round 5
// 174.261 us; speedup vs baseline: 1.0466x; 1.0466x over previous
//
#include <hip/hip_runtime.h>

// ---------------------------------------------------------------------------
// Causal MHSA. B=2, T=2048, D=1024, H=16, hd=64. fp32 in -> bf16 internal ->
// fp32 out. R16: best-of-each recombination — attn from R15 (47.7us: R11
// structure/mapping + cvt_pk packing), GEMMs from R14 (non-attn 125.9us:
// BK=32, fused V-transpose in gemm_qkv epilogue). BK=64 reverted (R15
// measured it -9us on non-attn vs R14).
// ---------------------------------------------------------------------------

#define T_SEQ 2048
#define D_MODEL 1024
#define NEG_BIG (-1.0e30f)
#define Q_SCALE 0.18033688f   // 0.125 * log2(e): attention uses exp2 directly

typedef float f32x4 __attribute__((ext_vector_type(4)));
typedef short s16x8 __attribute__((ext_vector_type(8)));
typedef __bf16 bf16x8 __attribute__((ext_vector_type(8)));

__device__ __forceinline__ f32x4 mfma16(s16x8 a, s16x8 b, f32x4 c) {
    // C[m][n]=sum_k A[m][k]B[n][k]; lane: a=A[m=l16][k=quad*8+j],
    // b=B[n=l16][k=quad*8+j]; C: col(l16)=n, row(quad*4+r)=m
    return __builtin_amdgcn_mfma_f32_16x16x32_bf16(
        __builtin_bit_cast(bf16x8, a), __builtin_bit_cast(bf16x8, b), c, 0, 0, 0);
}

__device__ __forceinline__ short f2bf(float f) {          // RNE
    unsigned int u = __float_as_uint(f);
    u += 0x7fffu + ((u >> 16) & 1u);
    return (short)(u >> 16);
}
__device__ __forceinline__ float bf2f(short s) {
    return __uint_as_float(((unsigned int)(unsigned short)s) << 16);
}
__device__ __forceinline__ unsigned cvt_pk_bf16(float lo, float hi) {
    unsigned r;
    asm("v_cvt_pk_bf16_f32 %0, %1, %2" : "=v"(r) : "v"(lo), "v"(hi));
    return r;
}

__device__ __forceinline__ void async_lds16(const short* g, short* l) {
    __builtin_amdgcn_global_load_lds(
        (const __attribute__((address_space(1))) unsigned int*)g,
        (__attribute__((address_space(3))) unsigned int*)l, 16, 0, 0);
}

// ---------------------------------------------------------------------------
// Fused canon: five fp32 inputs -> bf16, float4-vectorized, one launch.
// ---------------------------------------------------------------------------
#define N_X   4194304
#define N_WI  3145728
#define N_BI  3072
#define N_WO  1048576
#define N_BO  1024
#define V_X   (N_X  / 4)
#define V_WI  (N_WI / 4)
#define V_BI  (N_BI / 4)
#define V_WO  (N_WO / 4)
#define V_BO  (N_BO / 4)
#define V_TOT (V_X + V_WI + V_BI + V_WO + V_BO)

__global__ __launch_bounds__(256) void canon_all_kernel(
    const float* __restrict__ x, const float* __restrict__ wi,
    const float* __restrict__ bi, const float* __restrict__ wo,
    const float* __restrict__ bo,
    short* __restrict__ xb, short* __restrict__ wib, short* __restrict__ bib,
    short* __restrict__ wob, short* __restrict__ bob)
{
    int i = blockIdx.x * 256 + threadIdx.x;
    if (i >= V_TOT) return;
    const float* src; short* dst; int off;
    if      (i < V_X)                    { src = x;  dst = xb;  off = i; }
    else if (i < V_X+V_WI)               { src = wi; dst = wib; off = i - V_X; }
    else if (i < V_X+V_WI+V_BI)          { src = bi; dst = bib; off = i - V_X - V_WI; }
    else if (i < V_X+V_WI+V_BI+V_WO)     { src = wo; dst = wob; off = i - V_X - V_WI - V_BI; }
    else                                 { src = bo; dst = bob; off = i - V_X - V_WI - V_BI - V_WO; }
    float4 v = ((const float4*)src)[off];
    short4 o = { f2bf(v.x), f2bf(v.y), f2bf(v.z), f2bf(v.w) };
    ((short4*)dst)[off] = o;
}

// ---------------------------------------------------------------------------
// GEMM1 (m97 structure, BK=32): qkv = x @ w_in^T + b_in.
// q(xQ_SCALE)/k -> [B,H,T,64]; v -> Vt [B,H,64,T] (transpose fused: the
// r-loop's 4 acc values are t-consecutive -> one aligned short4 store).
// ---------------------------------------------------------------------------
__global__ __launch_bounds__(256) void gemm_qkv_kernel(
    const short* __restrict__ A, const short* __restrict__ B,
    const short* __restrict__ bias,
    short* __restrict__ qo, short* __restrict__ ko, short* __restrict__ vto)
{
    const int K = 1024;
    alignas(16) __shared__ short As[128][32];
    alignas(16) __shared__ short Bs[128][32];
    const int m0 = blockIdx.x * 128;
    const int n0 = blockIdx.y * 128;
    const int tid = threadIdx.x;
    const int lane = tid & 63;
    const int w = tid >> 6;
    const int wm = (w >> 1) * 64, wn = (w & 1) * 64;
    const int quad = lane >> 4, l16 = lane & 15;

    f32x4 acc[4][4];
    const f32x4 zero = {0.f, 0.f, 0.f, 0.f};
#pragma unroll
    for (int i = 0; i < 4; ++i)
#pragma unroll
        for (int j = 0; j < 4; ++j) acc[i][j] = zero;

    const int lrow = lane >> 2;
    const int lcol = (lane & 3) * 8;
    const short* gA0 = &A[(m0 + w*32      + lrow) * K + lcol];
    const short* gA1 = &A[(m0 + w*32 + 16 + lrow) * K + lcol];
    const short* gB0 = &B[(n0 + w*32      + lrow) * K + lcol];
    const short* gB1 = &B[(n0 + w*32 + 16 + lrow) * K + lcol];
    short* lA0 = &As[w*32][0];
    short* lA1 = &As[w*32 + 16][0];
    short* lB0 = &Bs[w*32][0];
    short* lB1 = &Bs[w*32 + 16][0];

    for (int k0 = 0; k0 < K; k0 += 32) {
        __syncthreads();
        async_lds16(gA0 + k0, lA0);
        async_lds16(gA1 + k0, lA1);
        async_lds16(gB0 + k0, lB0);
        async_lds16(gB1 + k0, lB1);
        __syncthreads();

        s16x8 af[4], bfr[4];
#pragma unroll
        for (int i = 0; i < 4; ++i) af[i]  = *(const s16x8*)&As[wm + i*16 + l16][quad*8];
#pragma unroll
        for (int j = 0; j < 4; ++j) bfr[j] = *(const s16x8*)&Bs[wn + j*16 + l16][quad*8];
#pragma unroll
        for (int i = 0; i < 4; ++i)
#pragma unroll
            for (int j = 0; j < 4; ++j)
                acc[i][j] = mfma16(af[i], bfr[j], acc[i][j]);
    }

#pragma unroll
    for (int j = 0; j < 4; ++j) {
        int n = n0 + wn + j*16 + l16;
        float bi = bf2f(bias[n]);
        int which = n >> 10;            // wave-uniform (16 consecutive n)
        int h = (n >> 6) & 15, d = n & 63;
        if (which < 2) {                // Q / K: [B,H,T,64]
            short* dst = (which == 0) ? qo : ko;
            float scl = (which == 0) ? Q_SCALE : 1.0f;
#pragma unroll
            for (int i = 0; i < 4; ++i) {
#pragma unroll
                for (int r = 0; r < 4; ++r) {
                    int m = m0 + wm + i*16 + quad*4 + r;
                    int b = m >> 11, t = m & 2047;
                    float v = (acc[i][j][r] + bi) * scl;
                    dst[(((b*16 + h) * 2048) + t) * 64 + d] = f2bf(v);
                }
            }
        } else {                        // V: write transposed [B,H,64,T]
#pragma unroll
            for (int i = 0; i < 4; ++i) {
                int m = m0 + wm + i*16 + quad*4;   // t0, %4 == 0
                int b = m >> 11, t0 = m & 2047;
                short4 o4 = { f2bf(acc[i][j][0] + bi), f2bf(acc[i][j][1] + bi),
                              f2bf(acc[i][j][2] + bi), f2bf(acc[i][j][3] + bi) };
                *(short4*)&vto[(((size_t)(b*16 + h) * 64) + d) * 2048 + t0] = o4;
            }
        }
    }
}

// ---------------------------------------------------------------------------
// Flash attention — R11 exact structure & mapping (proven 48.2us):
// dim3(32,32), bh=blockIdx.x (XCD=bh%8 L2 locality), qt=31-blockIdx.y
// (heavy-first). cvt_pk_bf16 packing (T12) for P and O (R15, -0.5us).
// ---------------------------------------------------------------------------
__global__ __launch_bounds__(256) void attn_kernel(
    const short* __restrict__ Q, const short* __restrict__ K,
    const short* __restrict__ Vt, short* __restrict__ ctx)
{
    alignas(16) __shared__ short Ks[64][72];      // [s][d]
    alignas(16) __shared__ short Vs[64][72];      // [d][s]
    alignas(16) __shared__ short Pl[4][16][72];   // per-wave [q][s]

    const int bh = blockIdx.x;
    const int qt = 31 - (int)blockIdx.y;          // heavy tiles first
    const int qbase = qt * 64;
    const int tid = threadIdx.x;
    const int w = tid >> 6, lane = tid & 63;
    const int quad = lane >> 4, l16 = lane & 15;
    const int b = bh >> 4, h = bh & 15;

    const short* Qb  = Q  + bh * T_SEQ * 64;
    const short* Kb  = K  + bh * T_SEQ * 64;
    const short* Vbt = Vt + (size_t)bh * 64 * T_SEQ;

    const short* qrow = Qb + (qbase + w*16 + l16) * 64;
    const s16x8 qa0 = *(const s16x8*)(qrow + quad*8);
    const s16x8 qa1 = *(const s16x8*)(qrow + 32 + quad*8);

    const f32x4 zero = {0.f, 0.f, 0.f, 0.f};
    f32x4 o[4];
#pragma unroll
    for (int dt = 0; dt < 4; ++dt) o[dt] = zero;
    float lsum = 0.f;

    const int sr  = tid >> 3;                     // 0..31
    const int scl = (tid & 7) * 8;                // 0..56
    const int qg  = qbase + w*16 + l16;

    // preload tile s0=0
    float4 kf0 = *(const float4*)&Kb[sr * 64 + scl];
    float4 kf1 = *(const float4*)&Kb[(sr + 32) * 64 + scl];
    float4 vf0 = *(const float4*)&Vbt[(size_t)sr * T_SEQ + scl];
    float4 vf1 = *(const float4*)&Vbt[(size_t)(sr + 32) * T_SEQ + scl];

    for (int s0 = 0; s0 <= qbase; s0 += 64) {
        __syncthreads();
        *(float4*)&Ks[sr][scl]    = kf0;
        *(float4*)&Ks[sr+32][scl] = kf1;
        *(float4*)&Vs[sr][scl]    = vf0;
        *(float4*)&Vs[sr+32][scl] = vf1;
        __syncthreads();

        if (s0 + 64 <= qbase) {                   // prefetch next tile
            kf0 = *(const float4*)&Kb[(s0 + 64 + sr) * 64 + scl];
            kf1 = *(const float4*)&Kb[(s0 + 64 + sr + 32) * 64 + scl];
            vf0 = *(const float4*)&Vbt[(size_t)sr * T_SEQ + s0 + 64 + scl];
            vf1 = *(const float4*)&Vbt[(size_t)(sr + 32) * T_SEQ + s0 + 64 + scl];
        }

        // S^T = K Q^T
#pragma unroll
        for (int sub = 0; sub < 4; ++sub) {
            s16x8 ka0 = *(const s16x8*)&Ks[sub*16 + l16][quad*8];
            s16x8 ka1 = *(const s16x8*)&Ks[sub*16 + l16][32 + quad*8];
            f32x4 S = mfma16(ka1, qa1, mfma16(ka0, qa0, zero));
            if (s0 == qbase) {                    // diagonal: causal mask
                int sb = s0 + sub*16 + quad*4;
#pragma unroll
                for (int r = 0; r < 4; ++r)
                    if (sb + r > qg) S[r] = NEG_BIG;
            }
            float p0 = exp2f(S[0]), p1 = exp2f(S[1]);
            float p2 = exp2f(S[2]), p3 = exp2f(S[3]);
            lsum += (p0 + p1) + (p2 + p3);
            uint2 pk;
            pk.x = cvt_pk_bf16(p0, p1);
            pk.y = cvt_pk_bf16(p2, p3);
            *(uint2*)&Pl[w][l16][sub*16 + quad*4] = pk;
        }
        // wave-private Pl: in-order within wave, no barrier

        // O^T += V^T P^T
        s16x8 pb0 = *(const s16x8*)&Pl[w][l16][quad*8];
        s16x8 pb1 = *(const s16x8*)&Pl[w][l16][32 + quad*8];
#pragma unroll
        for (int dt = 0; dt < 4; ++dt) {
            s16x8 va0 = *(const s16x8*)&Vs[dt*16 + l16][quad*8];
            s16x8 va1 = *(const s16x8*)&Vs[dt*16 + l16][32 + quad*8];
            o[dt] = mfma16(va1, pb1, mfma16(va0, pb0, o[dt]));
        }
    }

    lsum += __shfl_xor(lsum, 16, 64);
    lsum += __shfl_xor(lsum, 32, 64);
    float inv = 1.0f / lsum;
    int base = (b * T_SEQ + qg) * D_MODEL + h * 64;
#pragma unroll
    for (int dt = 0; dt < 4; ++dt) {
        uint2 pk;
        pk.x = cvt_pk_bf16(o[dt][0] * inv, o[dt][1] * inv);
        pk.y = cvt_pk_bf16(o[dt][2] * inv, o[dt][3] * inv);
        *(uint2*)&ctx[base + dt*16 + quad*4] = pk;
    }
}

// ---------------------------------------------------------------------------
// GEMM2 (BK=32): out = ctx @ w_out^T + b_out, fp32 store. 128x64, 512 blocks.
// ---------------------------------------------------------------------------
__global__ __launch_bounds__(256) void gemm_out_kernel(
    const short* __restrict__ A, const short* __restrict__ B,
    const short* __restrict__ bias, float* __restrict__ out)
{
    const int K = 1024;
    alignas(16) __shared__ short As[128][32];
    alignas(16) __shared__ short Bs[64][32];
    const int m0 = blockIdx.x * 128;
    const int n0 = blockIdx.y * 64;
    const int tid = threadIdx.x;
    const int lane = tid & 63;
    const int w = tid >> 6;
    const int wm = (w >> 1) * 64, wn = (w & 1) * 32;
    const int quad = lane >> 4, l16 = lane & 15;

    f32x4 acc[4][2];
    const f32x4 zero = {0.f, 0.f, 0.f, 0.f};
#pragma unroll
    for (int i = 0; i < 4; ++i)
#pragma unroll
        for (int j = 0; j < 2; ++j) acc[i][j] = zero;

    const int lrow = lane >> 2;
    const int lcol = (lane & 3) * 8;
    const short* gA0 = &A[(m0 + w*32      + lrow) * K + lcol];
    const short* gA1 = &A[(m0 + w*32 + 16 + lrow) * K + lcol];
    const short* gB0 = &B[(n0 + w*16 + lrow) * K + lcol];
    short* lA0 = &As[w*32][0];
    short* lA1 = &As[w*32 + 16][0];
    short* lB0 = &Bs[w*16][0];

    for (int k0 = 0; k0 < K; k0 += 32) {
        __syncthreads();
        async_lds16(gA0 + k0, lA0);
        async_lds16(gA1 + k0, lA1);
        async_lds16(gB0 + k0, lB0);
        __syncthreads();

        s16x8 af[4], bfr[2];
#pragma unroll
        for (int i = 0; i < 4; ++i) af[i]  = *(const s16x8*)&As[wm + i*16 + l16][quad*8];
#pragma unroll
        for (int j = 0; j < 2; ++j) bfr[j] = *(const s16x8*)&Bs[wn + j*16 + l16][quad*8];
#pragma unroll
        for (int i = 0; i < 4; ++i)
#pragma unroll
            for (int j = 0; j < 2; ++j)
                acc[i][j] = mfma16(af[i], bfr[j], acc[i][j]);
    }

#pragma unroll
    for (int j = 0; j < 2; ++j) {
        int n = n0 + wn + j*16 + l16;
        float bi = bf2f(bias[n]);
#pragma unroll
        for (int i = 0; i < 4; ++i) {
#pragma unroll
            for (int r = 0; r < 4; ++r) {
                int m = m0 + wm + i*16 + quad*4 + r;
                out[m * 1024 + n] = acc[i][j][r] + bi;
            }
        }
    }
}

// ---------------------------------------------------------------------------
extern "C" void kernel_launch(void* const* d_in, const int* in_sizes, int n_in,
                              void* d_out, int out_size, void* d_ws, size_t ws_size,
                              hipStream_t stream) {
    float* out = (float*)d_out;
    char* ws = (char*)d_ws;

    const size_t MB = 1u << 20;
    short* xb     = (short*)(ws);            // 8 MB
    short* w_inb  = (short*)(ws + 8*MB);     // 6 MB
    short* b_inb  = (short*)(ws + 14*MB);
    short* w_outb = (short*)(ws + 15*MB);    // 2 MB
    short* b_outb = (short*)(ws + 17*MB);
    short* qb     = (short*)(ws + 18*MB);    // 8 MB [B,H,T,64]
    short* kb     = (short*)(ws + 26*MB);    // 8 MB [B,H,T,64]
    short* vtb    = (short*)(ws + 34*MB);    // 8 MB [B,H,64,T] (direct from gemm)
    short* ctxb   = (short*)(ws + 42*MB);    // 8 MB [B,T,D]

    canon_all_kernel<<<(V_TOT + 255) / 256, 256, 0, stream>>>(
        (const float*)d_in[0], (const float*)d_in[1], (const float*)d_in[2],
        (const float*)d_in[3], (const float*)d_in[4],
        xb, w_inb, b_inb, w_outb, b_outb);

    gemm_qkv_kernel<<<dim3(32, 24), 256, 0, stream>>>(xb, w_inb, b_inb, qb, kb, vtb);
    attn_kernel<<<dim3(32, 32), 256, 0, stream>>>(qb, kb, vtb, ctxb);
    gemm_out_kernel<<<dim3(32, 16), 256, 0, stream>>>(ctxb, w_outb, b_outb, out);
}